// Round 1
// 268.889 us; speedup vs baseline: 1.0195x; 1.0195x over previous
//
#include <hip/hip_runtime.h>
#include <math.h>

// GAU attention: LN -> silu(x@W^T+b) x4 -> P=relu^2(QK^T/sqrt(T)) -> AV=P@V -> (U*AV)@Wo^T+bo
// R12: replace barrier-free per-wave global streaming with the m97 structure:
//  - async global_load_lds (width 16) stages each (strip,kf) 4KB chunk into
//    double-buffered LDS; waves share fragments via LDS (halves L1/L2 traffic,
//    removes per-fragment VALU address math).
//  - ds_read_b128 fragment reads (lane*16 within 1KB frag = conflict-free m97 pattern).
//  - one barrier per kf-step; packed kf-major global layout is already contiguous
//    per (strip,kf) so LDS stays linear (wave-uniform base + lane*16 constraint OK).
//  - epilogues / packing / XCD remap / ni-outer MFMA order unchanged (bit-identical math).

typedef __attribute__((ext_vector_type(8))) short short8;
typedef __attribute__((ext_vector_type(4))) float floatx4;

constexpr int HD = 768;
constexpr int TT = 2048;
constexpr long WElem = 589824;     // 768*768
constexpr long QKpb  = 1572864;    // 2048*768 shorts per batch
constexpr long Ppb   = 4194304;    // 2048*2048 shorts per batch

__device__ __forceinline__ short f2bf(float x) {
  unsigned u = __builtin_bit_cast(unsigned, x);
  u = u + 0x7fffu + ((u >> 16) & 1u);   // RNE
  return (short)(u >> 16);
}
__device__ __forceinline__ float bf2f(short s) {
  unsigned u = ((unsigned)(unsigned short)s) << 16;
  return __builtin_bit_cast(float, u);
}

// kf-major packed offset (in shorts) of element (i, c) of a row-major [R x C]
// matrix, KF = C/32. Layout: [strip = i>>6][kf = c>>5][frag mi = (i>>4)&3][512].
// Within-frag: lane = ((c&31)>>3)*16 + (i&15), elem = c&7.
__device__ __forceinline__ long pL(int i, int c, int KF) {
  return (((long)(i >> 6) * KF + (c >> 5)) * 4 + ((i >> 4) & 3)) * 512 +
         ((c & 31) >> 3) * 128 + (i & 15) * 8 + (c & 7);
}

typedef __attribute__((address_space(1))) void void_g;
typedef __attribute__((address_space(3))) void void_l;
__device__ __forceinline__ void gload16(const void* g, void* l) {
  __builtin_amdgcn_global_load_lds((const void_g*)g, (void_l*)l, 16, 0, 0);
}

// ---------------- LayerNorm + bf16 cast, writes x in packed-frag order ------------
__global__ __launch_bounds__(256) void ln_kernel(
    const float* __restrict__ x, const float* __restrict__ g,
    const float* __restrict__ b, short* __restrict__ out) {
  int row = blockIdx.x;
  const float* xr = x + (long)row * HD;
  int t = threadIdx.x;
  float v0 = xr[t], v1 = xr[t + 256], v2 = xr[t + 512];
  float s = v0 + v1 + v2;
  float ss = v0 * v0 + v1 * v1 + v2 * v2;
#pragma unroll
  for (int o = 32; o > 0; o >>= 1) {
    s += __shfl_down(s, o);
    ss += __shfl_down(ss, o);
  }
  __shared__ float red[8];
  int wid = t >> 6;
  if ((t & 63) == 0) { red[wid] = s; red[4 + wid] = ss; }
  __syncthreads();
  float S = red[0] + red[1] + red[2] + red[3];
  float SS = red[4] + red[5] + red[6] + red[7];
  float mean = S * (1.0f / HD);
  float var = SS * (1.0f / HD) - mean * mean;
  float rstd = rsqrtf(var + 1e-5f);
  out[pL(row, t, 24)]       = f2bf((v0 - mean) * rstd * g[t]       + b[t]);
  out[pL(row, t + 256, 24)] = f2bf((v1 - mean) * rstd * g[t + 256] + b[t + 256]);
  out[pL(row, t + 512, 24)] = f2bf((v2 - mean) * rstd * g[t + 512] + b[t + 512]);
}

// ---------------- fp32 -> packed bf16 weights + bias concat ------------------------
__global__ __launch_bounds__(256) void convert_kernel(
    const float* __restrict__ wu, const float* __restrict__ wq,
    const float* __restrict__ wk, const float* __restrict__ wv,
    const float* __restrict__ wo,
    const float* __restrict__ bu, const float* __restrict__ bq,
    const float* __restrict__ bk, const float* __restrict__ bv,
    short* __restrict__ Wb, float* __restrict__ bcat) {
  long i = (long)blockIdx.x * 256 + threadIdx.x;
  if (i < 5 * WElem) {
    int which = (int)(i / WElem);
    long off = i - (long)which * WElem;
    const float* src = which == 0 ? wu : which == 1 ? wq : which == 2 ? wk
                     : which == 3 ? wv : wo;
    int n = (int)(off / HD), k = (int)(off - (long)n * HD);
    Wb[(long)which * WElem + pL(n, k, 24)] = f2bf(src[off]);
  }
  if (i < 4 * HD) {
    int which = (int)(i / HD);
    int off = (int)(i - which * HD);
    const float* src = which == 0 ? bu : which == 1 ? bq : which == 2 ? bk : bv;
    bcat[i] = src[off];
  }
}

// ---------------- LDS-staged GEMM (m97 structure) -----------------------------------
// 4 waves arranged WM x WN (WM = 4/WN); wave tile 64 x (TN*16); block BM=128 x BN.
// 1-D grid, XCD-aware decode. Per kf-step: async global_load_lds of next (A,B)
// k-slab into ping-pong LDS, ds_read_b128 frags of current slab, 16 MFMAs/wave,
// one barrier (compiler drains vmcnt+lgkmcnt there).
template <int EPI, int KF, int GZ, int TN, int WN, int GY>
__global__ __launch_bounds__(256, 3) void wgemm(
    const short* __restrict__ Ag, const short* __restrict__ Bg,
    long sAz, long sBz,
    short* __restrict__ o0, short* __restrict__ o1,
    short* __restrict__ o2, short* __restrict__ o3,
    float* __restrict__ outf, const float* __restrict__ bias,
    const short* __restrict__ umul) {
  constexpr int TM = 4;
  constexpr int WM = 4 / WN;                 // 2
  constexpr int NSA = WM * TM / 4;           // 2 strips (BM = 128 rows)
  constexpr int NSB = WN * TN / 4;           // 2 (TN=4, BN=128) or 1 (TN=2, BN=64)
  constexpr int GYX = (GZ == 1) ? GY / 8 : GY / 2;   // by-range per XCD
  int f = blockIdx.x;
  int xcd = f & 7, i = f >> 3;
  int bx = i / GYX, byo = i % GYX;
  int z, by;
  if constexpr (GZ == 1) { z = 0;        by = xcd * GYX + byo; }
  else                   { z = xcd >> 1; by = (xcd & 1) * GYX + byo; }

  int t = threadIdx.x, w = t >> 6, lane = t & 63;
  int qd = lane >> 4, l15 = lane & 15;
  int wm = w / WN, wn = w % WN;
  int mf0 = (by * WM + wm) * TM;               // frag-row index
  int nf0 = (bx * WN + wn) * TN;               // frag-col index

  __shared__ __align__(16) short ldsA[2][NSA * 2048];
  __shared__ __align__(16) short ldsB[2][NSB * 2048];

  // staging sources: (strip, kf) chunk = contiguous 4096 B; wave w owns KB w of
  // each chunk; lane supplies 16 B. LDS dest is wave-uniform base (+lane*16 by HW).
  const char* aG = (const char*)(Ag + (long)z * sAz) +
                   (long)(by * NSA) * KF * 4096 + w * 1024 + lane * 16;
  const char* bG = (const char*)(Bg + (long)z * sBz) +
                   (long)(bx * NSB) * KF * 4096 + w * 1024 + lane * 16;
  char* lA0 = (char*)&ldsA[0][0] + w * 1024;
  char* lB0 = (char*)&ldsB[0][0] + w * 1024;

#define STAGE(p, kf)                                                          \
  {                                                                           \
    _Pragma("unroll") for (int s = 0; s < NSA; s++)                           \
        gload16(aG + ((long)s * KF + (kf)) * 4096,                            \
                lA0 + (p) * (NSA * 4096) + s * 4096);                         \
    _Pragma("unroll") for (int s = 0; s < NSB; s++)                           \
        gload16(bG + ((long)s * KF + (kf)) * 4096,                            \
                lB0 + (p) * (NSB * 4096) + s * 4096);                         \
  }

  floatx4 acc[TM][TN] = {};
  const char* fA = (const char*)&ldsA[0][0] + (wm * TM) * 1024 + lane * 16;
  const char* fB = (const char*)&ldsB[0][0] + (wn * TN) * 1024 + lane * 16;

  STAGE(0, 0);
  __syncthreads();                            // vmcnt(0) drain -> buf0 ready
#pragma unroll 2
  for (int kf = 0; kf < KF; ++kf) {
    int p = kf & 1;
    if (kf + 1 < KF) STAGE(p ^ 1, kf + 1);    // async prefetch into other buffer
    short8 a[TM], b[TN];
#pragma unroll
    for (int mi = 0; mi < TM; mi++)
      a[mi] = *(const short8*)(fA + p * (NSA * 4096) + mi * 1024);
#pragma unroll
    for (int ni = 0; ni < TN; ni++)
      b[ni] = *(const short8*)(fB + p * (NSB * 4096) + ni * 1024);
    // ni-outer MFMA order (first group ready after a0..a3 + b0)
#pragma unroll
    for (int ni = 0; ni < TN; ni++)
#pragma unroll
      for (int mi = 0; mi < TM; mi++)
        acc[mi][ni] = __builtin_amdgcn_mfma_f32_16x16x32_bf16(
            a[mi], b[ni], acc[mi][ni], 0, 0, 0);
    __syncthreads();   // all reads of buf p done + prefetch of p^1 landed
  }
#undef STAGE

  // epilogue: lane holds D[row = qd*4+r][col = l15] per 16x16 frag
#pragma unroll
  for (int mi = 0; mi < TM; mi++)
#pragma unroll
    for (int ni = 0; ni < TN; ni++) {
      int mB = (mf0 + mi) * 16 + qd * 4;
      int col = (nf0 + ni) * 16 + l15;
#pragma unroll
      for (int r = 0; r < 4; r++) {
        int m = mB + r;
        float v = acc[mi][ni][r];
        if constexpr (EPI == 0) {
          v += bias[col];
          v = v / (1.0f + __expf(-v));  // silu
          short sv = f2bf(v);
          int which = col / HD;
          int d = col - which * HD;
          int batch = m >> 11, ii = m & (TT - 1);
          if (which == 0)      o0[(long)m * HD + d] = sv;                      // U row-major
          else if (which == 1) o1[(long)batch * QKpb + pL(ii, d, 24)] = sv;    // Q pack
          else if (which == 2) o2[(long)batch * QKpb + pL(ii, d, 24)] = sv;    // K pack
          else                 o3[(long)batch * QKpb + pL(d, ii, 64)] = sv;    // Vt pack
        } else if constexpr (EPI == 1) {
          v *= 0.022097086912079608f;   // 1/sqrt(2048)
          v = fmaxf(v, 0.0f);
          v = v * v;
          o0[(long)z * Ppb + pL(m, col, 64)] = f2bf(v);                        // P pack
        } else if constexpr (EPI == 2) {
          long gm = (long)z * TT + m;
          float um = bf2f(umul[gm * HD + col]);
          o0[pL((int)gm, col, 24)] = f2bf(v * um);                             // G pack
        } else {
          outf[(long)m * HD + col] = v + bias[col];
        }
      }
    }
}

extern "C" void kernel_launch(void* const* d_in, const int* in_sizes, int n_in,
                              void* d_out, int out_size, void* d_ws, size_t ws_size,
                              hipStream_t stream) {
  (void)in_sizes; (void)n_in; (void)out_size; (void)ws_size;
  const float* hid = (const float*)d_in[0];
  const float* lng = (const float*)d_in[1];
  const float* lnb = (const float*)d_in[2];
  const float* Wu  = (const float*)d_in[3];
  const float* bu  = (const float*)d_in[4];
  const float* Wq  = (const float*)d_in[5];
  const float* bq  = (const float*)d_in[6];
  const float* Wk  = (const float*)d_in[7];
  const float* bk  = (const float*)d_in[8];
  const float* Wv  = (const float*)d_in[9];
  const float* bv  = (const float*)d_in[10];
  const float* Wo  = (const float*)d_in[11];
  const float* bo  = (const float*)d_in[12];

  // workspace layout (bytes); packed buffers
  char* ws = (char*)d_ws;
  short* Wb   = (short*)(ws);                 // 5*589824 bf16 = 5,898,240 B (packed)
  float* bcat = (float*)(ws + 5898240);       // 3072 fp32     =    12,288 B
  short* xbf  = (short*)(ws + 5910528);       // x pack, 12,582,912 B
  short* Ub   = (short*)(ws + 18493440);      // U row-major, 12,582,912 B
  short* Qb   = (short*)(ws + 31076352);      // Q pack, 12,582,912 B
  short* Kb   = (short*)(ws + 43659264);      // K pack, 12,582,912 B
  short* Vt   = (short*)(ws + 56242176);      // Vt pack, 12,582,912 B
  short* Pb   = (short*)(ws + 68825088);      // P pack, 33,554,432 B
  short* Gb   = (short*)(ws + 102379520);     // G pack, 12,582,912 B (total ~115 MB)

  convert_kernel<<<11520, 256, 0, stream>>>(Wu, Wq, Wk, Wv, Wo, bu, bq, bk, bv, Wb, bcat);
  ln_kernel<<<8192, 256, 0, stream>>>(hid, lng, lnb, xbf);

  // U,Q,K,V = silu(x @ Wcat^T + bcat): block 128x128 (2x2), GY=64, GX=24
  wgemm<0, 24, 1, 4, 2, 64><<<1536, 256, 0, stream>>>(
      xbf, Wb, 0, 0, Ub, Qb, Kb, Vt, nullptr, bcat, nullptr);

  // P = relu(QK^T/sqrt(T))^2 per batch: block 128x128 (2x2), GY=16, GX=16, GZ=4
  wgemm<1, 24, 4, 4, 2, 16><<<1024, 256, 0, stream>>>(
      Qb, Kb, QKpb, QKpb, Pb, nullptr, nullptr, nullptr, nullptr, nullptr, nullptr);

  // G = (P @ V) * U per batch: block 128x64 (2x2, TN=2), GY=16, GX=12, GZ=4
  wgemm<2, 64, 4, 2, 2, 16><<<768, 256, 0, stream>>>(
      Pb, Vt, Ppb, QKpb, Gb, nullptr, nullptr, nullptr, nullptr, nullptr, Ub);

  // out = G @ Wo^T + bo: block 128x64 (2x2, TN=2), GY=64, GX=12, GZ=1, fp32 out
  wgemm<3, 24, 1, 2, 2, 64><<<768, 256, 0, stream>>>(
      Gb, Wb + 4 * WElem, 0, 0, nullptr, nullptr, nullptr, nullptr,
      (float*)d_out, bo, nullptr);
}

// Round 2
// 258.861 us; speedup vs baseline: 1.0590x; 1.0387x over previous
//
#include <hip/hip_runtime.h>
#include <math.h>

// GAU attention: LN -> silu(x@W^T+b) x4 -> P=relu^2(QK^T/sqrt(T)) -> AV=P@V -> (U*AV)@Wo^T+bo
// R13: uniform TN=4 (128x128 blocks) for ALL GEMMs + LDS-staged vectorized epilogue.
//  - R12 showed TN=2 staged kernels regressed (12KB staged / 8 MFMA per kf + 64
//    barrier drains for G). TN=4 restores the measured-good 8-read/16-MFMA ratio.
//  - Epilogue was scalar-scatter (64 x 2B stores + 64 x pL addr calc per lane,
//    ~2x the K-loop's MFMA cycles -> VALUBusy 38% > MfmaUtil 22%). Now: stage acc
//    into LDS tiles (XOR swizzle, <=2-way banks = free), re-read row-contiguous
//    16B chunks, store short8/float4 (8 vector stores/lane). pL computed once per
//    8 outputs. V tiles stored transposed (which is block-uniform: 768/128=6).
//  - Numerics bit-identical: bf16 rounded exactly once per output (EPI 2/3 stage
//    f32 scratch in two passes; G's u-multiply applied to exact f32 acc).

typedef __attribute__((ext_vector_type(8))) short short8;
typedef __attribute__((ext_vector_type(4))) short short4v;
typedef __attribute__((ext_vector_type(4))) float floatx4;

constexpr int HD = 768;
constexpr int TT = 2048;
constexpr long WElem = 589824;     // 768*768
constexpr long QKpb  = 1572864;    // 2048*768 shorts per batch
constexpr long Ppb   = 4194304;    // 2048*2048 shorts per batch

__device__ __forceinline__ short f2bf(float x) {
  unsigned u = __builtin_bit_cast(unsigned, x);
  u = u + 0x7fffu + ((u >> 16) & 1u);   // RNE
  return (short)(u >> 16);
}
__device__ __forceinline__ float bf2f(short s) {
  unsigned u = ((unsigned)(unsigned short)s) << 16;
  return __builtin_bit_cast(float, u);
}

// kf-major packed offset (in shorts) of element (i, c) of a row-major [R x C]
// matrix, KF = C/32. Layout: [strip = i>>6][kf = c>>5][frag mi = (i>>4)&3][512].
// Within-frag: lane = ((c&31)>>3)*16 + (i&15), elem = c&7.
__device__ __forceinline__ long pL(int i, int c, int KF) {
  return (((long)(i >> 6) * KF + (c >> 5)) * 4 + ((i >> 4) & 3)) * 512 +
         ((c & 31) >> 3) * 128 + (i & 15) * 8 + (c & 7);
}

typedef __attribute__((address_space(1))) void void_g;
typedef __attribute__((address_space(3))) void void_l;
__device__ __forceinline__ void gload16(const void* g, void* l) {
  __builtin_amdgcn_global_load_lds((const void_g*)g, (void_l*)l, 16, 0, 0);
}

// ---------------- LayerNorm + bf16 cast, writes x in packed-frag order ------------
__global__ __launch_bounds__(256) void ln_kernel(
    const float* __restrict__ x, const float* __restrict__ g,
    const float* __restrict__ b, short* __restrict__ out) {
  int row = blockIdx.x;
  const float* xr = x + (long)row * HD;
  int t = threadIdx.x;
  float v0 = xr[t], v1 = xr[t + 256], v2 = xr[t + 512];
  float s = v0 + v1 + v2;
  float ss = v0 * v0 + v1 * v1 + v2 * v2;
#pragma unroll
  for (int o = 32; o > 0; o >>= 1) {
    s += __shfl_down(s, o);
    ss += __shfl_down(ss, o);
  }
  __shared__ float red[8];
  int wid = t >> 6;
  if ((t & 63) == 0) { red[wid] = s; red[4 + wid] = ss; }
  __syncthreads();
  float S = red[0] + red[1] + red[2] + red[3];
  float SS = red[4] + red[5] + red[6] + red[7];
  float mean = S * (1.0f / HD);
  float var = SS * (1.0f / HD) - mean * mean;
  float rstd = rsqrtf(var + 1e-5f);
  out[pL(row, t, 24)]       = f2bf((v0 - mean) * rstd * g[t]       + b[t]);
  out[pL(row, t + 256, 24)] = f2bf((v1 - mean) * rstd * g[t + 256] + b[t + 256]);
  out[pL(row, t + 512, 24)] = f2bf((v2 - mean) * rstd * g[t + 512] + b[t + 512]);
}

// ---------------- fp32 -> packed bf16 weights + bias concat ------------------------
__global__ __launch_bounds__(256) void convert_kernel(
    const float* __restrict__ wu, const float* __restrict__ wq,
    const float* __restrict__ wk, const float* __restrict__ wv,
    const float* __restrict__ wo,
    const float* __restrict__ bu, const float* __restrict__ bq,
    const float* __restrict__ bk, const float* __restrict__ bv,
    short* __restrict__ Wb, float* __restrict__ bcat) {
  long i = (long)blockIdx.x * 256 + threadIdx.x;
  if (i < 5 * WElem) {
    int which = (int)(i / WElem);
    long off = i - (long)which * WElem;
    const float* src = which == 0 ? wu : which == 1 ? wq : which == 2 ? wk
                     : which == 3 ? wv : wo;
    int n = (int)(off / HD), k = (int)(off - (long)n * HD);
    Wb[(long)which * WElem + pL(n, k, 24)] = f2bf(src[off]);
  }
  if (i < 4 * HD) {
    int which = (int)(i / HD);
    int off = (int)(i - which * HD);
    const float* src = which == 0 ? bu : which == 1 ? bq : which == 2 ? bk : bv;
    bcat[i] = src[off];
  }
}

// ---------------- LDS-staged GEMM (m97 structure) + vectorized epilogue ------------
// 4 waves 2x2; wave tile 64x64 (TM=TN=4); block 128x128. Per kf-step: async
// global_load_lds of next k-slab into ping-pong LDS, ds_read_b128 frags, 16
// MFMAs/wave, one barrier. Epilogue stages acc through the same LDS.
template <int EPI, int KF, int GZ, int TN, int WN, int GY>
__global__ __launch_bounds__(256, 3) void wgemm(
    const short* __restrict__ Ag, const short* __restrict__ Bg,
    long sAz, long sBz,
    short* __restrict__ o0, short* __restrict__ o1,
    short* __restrict__ o2, short* __restrict__ o3,
    float* __restrict__ outf, const float* __restrict__ bias,
    const short* __restrict__ umul) {
  constexpr int TM = 4;
  constexpr int WM = 4 / WN;                 // 2
  constexpr int NSA = WM * TM / 4;           // 2 strips (BM = 128 rows)
  constexpr int NSB = WN * TN / 4;           // 2 strips (BN = 128 cols)
  static_assert(TN == 4, "epilogue assumes TN=4");
  constexpr int LDSA_B = NSA * 4096 * 2;     // 16 KB (2 buffers)
  constexpr int LDSB_B = NSB * 4096 * 2;     // 16 KB
  constexpr int GYX = (GZ == 1) ? GY / 8 : GY / 2;   // by-range per XCD
  int f = blockIdx.x;
  int xcd = f & 7, i = f >> 3;
  int bx = i / GYX, byo = i % GYX;
  int z, by;
  if constexpr (GZ == 1) { z = 0;        by = xcd * GYX + byo; }
  else                   { z = xcd >> 1; by = (xcd & 1) * GYX + byo; }

  int t = threadIdx.x, w = t >> 6, lane = t & 63;
  int qd = lane >> 4, l15 = lane & 15;
  int wm = w / WN, wn = w % WN;
  int mf0 = (by * WM + wm) * TM;               // frag-row index
  int nf0 = (bx * WN + wn) * TN;               // frag-col index

  __shared__ __align__(16) char smem[LDSA_B + LDSB_B];   // 32 KB

  const char* aG = (const char*)(Ag + (long)z * sAz) +
                   (long)(by * NSA) * KF * 4096 + w * 1024 + lane * 16;
  const char* bG = (const char*)(Bg + (long)z * sBz) +
                   (long)(bx * NSB) * KF * 4096 + w * 1024 + lane * 16;
  char* lA0 = smem + w * 1024;
  char* lB0 = smem + LDSA_B + w * 1024;

#define STAGE(p, kf)                                                          \
  {                                                                           \
    _Pragma("unroll") for (int s = 0; s < NSA; s++)                           \
        gload16(aG + ((long)s * KF + (kf)) * 4096,                            \
                lA0 + (p) * (NSA * 4096) + s * 4096);                         \
    _Pragma("unroll") for (int s = 0; s < NSB; s++)                           \
        gload16(bG + ((long)s * KF + (kf)) * 4096,                            \
                lB0 + (p) * (NSB * 4096) + s * 4096);                         \
  }

  floatx4 acc[TM][TN] = {};
  const char* fA = smem + (wm * TM) * 1024 + lane * 16;
  const char* fB = smem + LDSA_B + (wn * TN) * 1024 + lane * 16;

  STAGE(0, 0);
  __syncthreads();
#pragma unroll 2
  for (int kf = 0; kf < KF; ++kf) {
    int p = kf & 1;
    if (kf + 1 < KF) STAGE(p ^ 1, kf + 1);
    short8 a[TM], b[TN];
#pragma unroll
    for (int mi = 0; mi < TM; mi++)
      a[mi] = *(const short8*)(fA + p * (NSA * 4096) + mi * 1024);
#pragma unroll
    for (int ni = 0; ni < TN; ni++)
      b[ni] = *(const short8*)(fB + p * (NSB * 4096) + ni * 1024);
#pragma unroll
    for (int ni = 0; ni < TN; ni++)
#pragma unroll
      for (int mi = 0; mi < TM; mi++)
        acc[mi][ni] = __builtin_amdgcn_mfma_f32_16x16x32_bf16(
            a[mi], b[ni], acc[mi][ni], 0, 0, 0);
    __syncthreads();
  }
#undef STAGE

  // ---- epilogue ----
  // Stage outputs into per-wave 8KB LDS tiles (XOR swizzle: col-block bit3 ^= row
  // bit2 -> <=2-way banks on both sides), re-read as row-contiguous 16B chunks,
  // store vectorized. bf16 rounding exactly once per output.
  int qd4 = qd * 4;
  if constexpr (EPI == 0 || EPI == 1) {
    short* scw = (short*)(smem + w * 8192);        // 16 tiles x 512 B
    const bool vt = (EPI == 0) && (bx >= 18);      // which==3 (V): transposed tiles
#pragma unroll
    for (int mi = 0; mi < TM; mi++)
#pragma unroll
      for (int ni = 0; ni < TN; ni++) {
        int col = (nf0 + ni) * 16 + l15;
        short* tile = scw + (mi * TN + ni) * 256;
        short4v pk;
#pragma unroll
        for (int r = 0; r < 4; r++) {
          float v = acc[mi][ni][r];
          if constexpr (EPI == 0) {
            v += bias[col];
            v = v / (1.0f + __expf(-v));            // silu
          } else {
            v *= 0.022097086912079608f;             // 1/sqrt(2048)
            v = fmaxf(v, 0.0f);
            v = v * v;
          }
          short sv = f2bf(v);
          if (!vt) tile[(qd4 + r) * 16 + (l15 ^ (((qd4 + r) & 4) << 1))] = sv;
          else pk[r] = sv;
        }
        if (vt)   // transposed tile[col][row]; rows qd4..qd4+3 contiguous -> b64
          *(short4v*)&tile[l15 * 16 + (qd4 ^ ((l15 & 4) << 1))] = pk;
      }
    __syncthreads();
    int rw = lane & 15, g = (lane >> 4) & 1;
#pragma unroll
    for (int fp = 0; fp < 8; fp++) {
      int id = fp * 2 + (lane >> 5);
      int mi = id >> 2, ni = id & 3;
      const short* tile = scw + id * 256;
      short8 val = *(const short8*)&tile[rw * 16 + ((g ^ ((rw >> 2) & 1)) << 3)];
      if constexpr (EPI == 1) {
        int m = (mf0 + mi) * 16 + rw;
        int c0 = (nf0 + ni) * 16 + g * 8;
        *(short8*)&o0[(long)z * Ppb + pL(m, c0, 64)] = val;
      } else {
        if (!vt) {
          int m = (mf0 + mi) * 16 + rw;
          int c0 = (nf0 + ni) * 16 + g * 8;
          int which = bx / 6;                      // block-uniform
          int d0 = c0 - which * HD;
          int batch = m >> 11, ii = m & (TT - 1);
          if (which == 0)      *(short8*)&o0[(long)m * HD + d0] = val;
          else if (which == 1) *(short8*)&o1[(long)batch * QKpb + pL(ii, d0, 24)] = val;
          else                 *(short8*)&o2[(long)batch * QKpb + pL(ii, d0, 24)] = val;
        } else {
          int d = (nf0 + ni) * 16 + rw - 3 * HD;   // tile row = original col
          int m0 = (mf0 + mi) * 16 + g * 8;        // 8 consecutive output rows
          int batch = m0 >> 11, ii0 = m0 & (TT - 1);
          *(short8*)&o3[(long)batch * QKpb + pL(d, ii0, 64)] = val;
        }
      }
    }
  } else {
    // EPI 2/3: f32 scratch (no early rounding), two passes of 8 frags (8 KB/wave)
    float* scf = (float*)(smem + w * 8192);
#pragma unroll
    for (int half = 0; half < 2; half++) {
#pragma unroll
      for (int mi2 = 0; mi2 < 2; mi2++)
#pragma unroll
        for (int ni = 0; ni < TN; ni++) {
          float* tile = scf + (mi2 * TN + ni) * 256;
          int mi = half * 2 + mi2;
#pragma unroll
          for (int r = 0; r < 4; r++)
            tile[(qd4 + r) * 16 + (l15 ^ (((qd4 + r) & 4) << 1))] = acc[mi][ni][r];
        }
      __syncthreads();
      int rw = lane & 15, g4 = lane >> 4;
#pragma unroll
      for (int cp = 0; cp < 8; cp++) {
        int mi = half * 2 + (cp >> 2), ni = cp & 3;
        const float* tile = scf + cp * 256;
        floatx4 val = *(const floatx4*)&tile[rw * 16 + ((g4 ^ (((rw >> 2) & 1) << 1)) << 2)];
        int m = (mf0 + mi) * 16 + rw;
        int c0 = (nf0 + ni) * 16 + g4 * 4;
        if constexpr (EPI == 2) {
          long gm = (long)z * TT + m;
          short4v u = *(const short4v*)&umul[gm * HD + c0];
          short4v gv;
#pragma unroll
          for (int j = 0; j < 4; j++) gv[j] = f2bf(val[j] * bf2f(u[j]));
          *(short4v*)&o0[pL((int)gm, c0, 24)] = gv;
        } else {
          floatx4 bv = *(const floatx4*)&bias[c0];
          *(floatx4*)&outf[(long)m * HD + c0] = val + bv;
        }
      }
      __syncthreads();
    }
  }
}

extern "C" void kernel_launch(void* const* d_in, const int* in_sizes, int n_in,
                              void* d_out, int out_size, void* d_ws, size_t ws_size,
                              hipStream_t stream) {
  (void)in_sizes; (void)n_in; (void)out_size; (void)ws_size;
  const float* hid = (const float*)d_in[0];
  const float* lng = (const float*)d_in[1];
  const float* lnb = (const float*)d_in[2];
  const float* Wu  = (const float*)d_in[3];
  const float* bu  = (const float*)d_in[4];
  const float* Wq  = (const float*)d_in[5];
  const float* bq  = (const float*)d_in[6];
  const float* Wk  = (const float*)d_in[7];
  const float* bk  = (const float*)d_in[8];
  const float* Wv  = (const float*)d_in[9];
  const float* bv  = (const float*)d_in[10];
  const float* Wo  = (const float*)d_in[11];
  const float* bo  = (const float*)d_in[12];

  // workspace layout (bytes); packed buffers
  char* ws = (char*)d_ws;
  short* Wb   = (short*)(ws);                 // 5*589824 bf16 = 5,898,240 B (packed)
  float* bcat = (float*)(ws + 5898240);       // 3072 fp32     =    12,288 B
  short* xbf  = (short*)(ws + 5910528);       // x pack, 12,582,912 B
  short* Ub   = (short*)(ws + 18493440);      // U row-major, 12,582,912 B
  short* Qb   = (short*)(ws + 31076352);      // Q pack, 12,582,912 B
  short* Kb   = (short*)(ws + 43659264);      // K pack, 12,582,912 B
  short* Vt   = (short*)(ws + 56242176);      // Vt pack, 12,582,912 B
  short* Pb   = (short*)(ws + 68825088);      // P pack, 33,554,432 B
  short* Gb   = (short*)(ws + 102379520);     // G pack, 12,582,912 B (total ~115 MB)

  convert_kernel<<<11520, 256, 0, stream>>>(Wu, Wq, Wk, Wv, Wo, bu, bq, bk, bv, Wb, bcat);
  ln_kernel<<<8192, 256, 0, stream>>>(hid, lng, lnb, xbf);

  // U,Q,K,V = silu(x @ Wcat^T + bcat): block 128x128 (2x2), GY=64, GX=24
  wgemm<0, 24, 1, 4, 2, 64><<<1536, 256, 0, stream>>>(
      xbf, Wb, 0, 0, Ub, Qb, Kb, Vt, nullptr, bcat, nullptr);

  // P = relu(QK^T/sqrt(T))^2 per batch: block 128x128 (2x2), GY=16, GX=16, GZ=4
  wgemm<1, 24, 4, 4, 2, 16><<<1024, 256, 0, stream>>>(
      Qb, Kb, QKpb, QKpb, Pb, nullptr, nullptr, nullptr, nullptr, nullptr, nullptr);

  // G = (P @ V) * U per batch: block 128x128 (2x2, TN=4), GY=16, GX=6, GZ=4
  wgemm<2, 64, 4, 4, 2, 16><<<384, 256, 0, stream>>>(
      Pb, Vt, Ppb, QKpb, Gb, nullptr, nullptr, nullptr, nullptr, nullptr, Ub);

  // out = G @ Wo^T + bo: block 128x128 (2x2, TN=4), GY=64, GX=6, GZ=1, fp32 out
  wgemm<3, 24, 1, 4, 2, 64><<<384, 256, 0, stream>>>(
      Gb, Wb + 4 * WElem, 0, 0, nullptr, nullptr, nullptr, nullptr,
      (float*)d_out, bo, nullptr);
}